// Round 5
// baseline (222.086 us; speedup 1.0000x reference)
//
#include <hip/hip_runtime.h>
#include <math.h>

#define HPAD 72      // LDS row stride (shorts) for 64-wide rows; 144 B keeps 16B alignment
#define PPAD 40      // LDS row stride for 32-wide pssm rows (80 B, 16B-aligned)

typedef short bf16x8 __attribute__((ext_vector_type(8)));
typedef float f32x4  __attribute__((ext_vector_type(4)));

// round-to-nearest-even float -> bf16 bits
__device__ __forceinline__ unsigned short f2bf(float x) {
    unsigned int u = __float_as_uint(x);
    return (unsigned short)((u + 0x7FFFu + ((u >> 16) & 1u)) >> 16);
}
__device__ __forceinline__ float bf2f(unsigned short h) {
    return __uint_as_float(((unsigned int)h) << 16);
}
// RNE split (used in precompute where cost is irrelevant)
__device__ __forceinline__ void split2(float x, unsigned short& h, unsigned short& l) {
    h = f2bf(x);
    l = f2bf(x - bf2f(h));
}
// truncation split (cheap: hot path). hi = trunc(x), lo = RNE(x - hi).
// x - hi is exact (low mantissa bits); combined rel err ~2^-17.
__device__ __forceinline__ void split2t(float x, unsigned short& h, unsigned short& l) {
    unsigned int u = __float_as_uint(x);
    h = (unsigned short)(u >> 16);
    float r = x - __uint_as_float(u & 0xFFFF0000u);
    l = f2bf(r);
}

__device__ __forceinline__ float inv_norm3(float x, float y, float z) {
    float d = fmaf(x, x, fmaf(y, y, z * z));
    return rsqrtf(fmaxf(d, 1e-24f));
}
__device__ __forceinline__ float3 f3sub(float3 a, float3 b) {
    return make_float3(a.x - b.x, a.y - b.y, a.z - b.z);
}
__device__ __forceinline__ float3 f3cross(float3 a, float3 b) {
    return make_float3(a.y * b.z - a.z * b.y,
                       a.z * b.x - a.x * b.z,
                       a.x * b.y - a.y * b.x);
}
// NeRF frame with parallel normalizations (n from unnormalized w: same direction)
__device__ __forceinline__ void nerf_frame(const float3& A, const float3& Bv,
                                           const float3& C, float3& bc,
                                           float3& n, float3& m3) {
    float3 w  = f3sub(C, Bv);
    float3 v  = f3sub(Bv, A);
    float3 cr = f3cross(v, w);
    float iw = inv_norm3(w.x, w.y, w.z);
    float ic = inv_norm3(cr.x, cr.y, cr.z);
    bc = make_float3(w.x * iw, w.y * iw, w.z * iw);
    n  = make_float3(cr.x * ic, cr.y * ic, cr.z * ic);
    m3 = f3cross(n, bc);
}
__device__ __forceinline__ float3 nerf_place(const float3& C, const float3& bc,
                                             const float3& m3, const float3& n,
                                             float tx, float ty, float tz) {
    return make_float3(
        fmaf(m3.x, ty, fmaf(bc.x, tx, fmaf(n.x, tz, C.x))),
        fmaf(m3.y, ty, fmaf(bc.y, tx, fmaf(n.y, tz, C.y))),
        fmaf(m3.z, ty, fmaf(bc.z, tx, fmaf(n.z, tz, C.z))));
}

// ---------- prep: seqT (blocks 0..4) + split weight tables (block 5) ----------
// seqT[r][j] = seq_embed[r]@W0[0:16] + b0[j] + 0.5*sum_c W0p[c][j]
// (0.5 compensates centering pssm by -0.5 before split quantization)
// Tables are transposed [n][k] so an MFMA B-fragment is one 16B load.
__global__ __launch_bounds__(256) void prep_kernel(
    const float* __restrict__ se, const float* __restrict__ W0,
    const float* __restrict__ b0, const float* __restrict__ We,
    const float* __restrict__ W1, float* __restrict__ seqT,
    unsigned short* __restrict__ WeTH, unsigned short* __restrict__ WeTL,
    unsigned short* __restrict__ W0pTH, unsigned short* __restrict__ W0pTL,
    unsigned short* __restrict__ W1TH, unsigned short* __restrict__ W1TL) {
    int tid = threadIdx.x;
    if (blockIdx.x < 5) {
        int e = blockIdx.x * 256 + tid;   // 0..1279
        int r = e >> 6, j = e & 63;
        float acc = b0[j];
        #pragma unroll
        for (int k = 0; k < 16; ++k)
            acc = fmaf(se[r * 16 + k], W0[k * 64 + j], acc);
        float cs = 0.f;
        #pragma unroll
        for (int c = 0; c < 21; ++c) cs += W0[(272 + c) * 64 + j];
        seqT[r * 64 + j] = acc + 0.5f * cs;
    } else {
        #pragma unroll
        for (int i = 0; i < 16; ++i) {            // We: 64k x 64n
            int e = i * 256 + tid;
            int k = e >> 6, n = e & 63;
            unsigned short h, l; split2(We[k * 64 + n], h, l);
            WeTH[n * 64 + k] = h; WeTL[n * 64 + k] = l;
        }
        #pragma unroll
        for (int i = 0; i < 8; ++i) {             // W0p: 32k x 64n (k>=21 zero)
            int e = i * 256 + tid;
            int k = e >> 6, n = e & 63;
            float w = (k < 21) ? W0[(272 + k) * 64 + n] : 0.f;
            unsigned short h, l; split2(w, h, l);
            W0pTH[n * 32 + k] = h; W0pTL[n * 32 + k] = l;
        }
        #pragma unroll
        for (int i = 0; i < 4; ++i) {             // W1: 64k x 16c (c>=9 zero)
            int e = i * 256 + tid;
            int k = e >> 4, c = e & 15;
            float w = (c < 9) ? W1[k * 9 + c] : 0.f;
            unsigned short h, l; split2(w, h, l);
            W1TH[c * 64 + k] = h; W1TL[c * 64 + k] = l;
        }
    }
}

// ---------- kmer table: 10648x64 fp32, 4 rows/wave for occupancy ----------
// 666 blocks x 4 waves = 2664 waves (~10.4/CU): latency actually hidden,
// W0 slice re-read from L2 (~170 MB aggregate) is the new bound.
__global__ __launch_bounds__(256) void kmer_table_kernel(
    const float* __restrict__ emb, const float* __restrict__ W0,
    float* __restrict__ kt) {
    int j  = threadIdx.x & 63;
    int wv = threadIdx.x >> 6;
    int r0 = blockIdx.x * 16 + wv * 4;
    if (r0 >= 10648) return;    // wave-uniform exit
    float acc[4] = {0.f, 0.f, 0.f, 0.f};
    #pragma unroll 8
    for (int k = 0; k < 256; ++k) {
        float w = W0[(16 + k) * 64 + j];          // per-lane coalesced, L2-hot
        #pragma unroll
        for (int r = 0; r < 4; ++r)
            acc[r] = fmaf(emb[(r0 + r) * 256 + k], w, acc[r]);  // uniform -> s_load
    }
    #pragma unroll
    for (int r = 0; r < 4; ++r)
        kt[(r0 + r) * 64 + j] = acc[r];
}

// ---------- split-bf16 MFMA MLP ----------
// Block = 256 thr = 4 waves, M = 64 positions. Wave wv owns N-strip [16wv,16wv+16)
// for layers 0..2, M-tile wv for the head. A*B = Ah*Bh + Al*Bh + Ah*Bl, fp32 acc.
// Weights come pre-split from prep_kernel (12 x 16B L1-hot loads, zero VALU).
// Exact fp32 path: seqT/kmerT gathers enter the MFMA C operand directly.
__global__ __launch_bounds__(256, 3) void mlp_kernel(
    const int* __restrict__ seq, const int* __restrict__ kmer,
    const float* __restrict__ pssm,
    const float* __restrict__ seqT, const float* __restrict__ kmerT,
    const unsigned short* __restrict__ WeTH, const unsigned short* __restrict__ WeTL,
    const unsigned short* __restrict__ W0pTH, const unsigned short* __restrict__ W0pTL,
    const unsigned short* __restrict__ W1TH, const unsigned short* __restrict__ W1TL,
    const float* __restrict__ be, const float* __restrict__ b1,
    float* __restrict__ srf_t) {

    __shared__ __align__(16) unsigned short Hah[64][HPAD];   // H hi [m][k]
    __shared__ __align__(16) unsigned short Hal[64][HPAD];   // H lo [m][k]
    __shared__ __align__(16) unsigned short ovl[2][64][HPAD]; // pssm pair, then Hb pair
    __shared__ int sidx[64];
    __shared__ int kidx[64];

    unsigned short (*Ph)[PPAD] = (unsigned short(*)[PPAD])(&ovl[0][0][0]);
    unsigned short (*Pl)[PPAD] = (unsigned short(*)[PPAD])(&ovl[0][0][0] + 2560);
    unsigned short (*Hbh)[HPAD] = ovl[0];
    unsigned short (*Hbl)[HPAD] = ovl[1];

    const int tid  = threadIdx.x;
    const int lane = tid & 63;
    const int wv   = __builtin_amdgcn_readfirstlane(tid >> 6);  // 0..3
    const int q    = lane >> 4;
    const int c16  = lane & 15;
    const int m0   = blockIdx.x * 64;
    const int n    = wv * 16 + c16;   // my output column for layers 0..2

    // ---- stage indices + centered pssm (trunc-split) into LDS ----
    if (tid < 64) {
        sidx[tid] = seq[m0 + tid];
        kidx[tid] = kmer[m0 + tid];
    }
    for (int i = tid; i < 64 * 21; i += 256) {
        float v = pssm[m0 * 21 + i] - 0.5f;
        unsigned short h, l; split2t(v, h, l);
        Ph[i / 21][i % 21] = h;
        Pl[i / 21][i % 21] = l;
    }
    for (int i = tid; i < 64 * 11; i += 256) {   // zero K-pad cols 21..31
        Ph[i / 11][21 + (i % 11)] = 0;
        Pl[i / 11][21 + (i % 11)] = 0;
    }

    // ---- weight fragments: direct 16B loads from pre-split tables ----
    bf16x8 WeH[2], WeL[2], W1H[2], W1L[2], W0H, W0L;
    #pragma unroll
    for (int kk = 0; kk < 2; ++kk) {
        WeH[kk] = *(const bf16x8*)(WeTH + n * 64 + kk * 32 + q * 8);
        WeL[kk] = *(const bf16x8*)(WeTL + n * 64 + kk * 32 + q * 8);
        W1H[kk] = *(const bf16x8*)(W1TH + c16 * 64 + kk * 32 + q * 8);
        W1L[kk] = *(const bf16x8*)(W1TL + c16 * 64 + kk * 32 + q * 8);
    }
    W0H = *(const bf16x8*)(W0pTH + n * 32 + q * 8);
    W0L = *(const bf16x8*)(W0pTL + n * 32 + q * 8);
    const float be_n = be[n];
    const float b1h  = (c16 < 9) ? b1[c16] : 0.f;
    __syncthreads();

    // ---- layer 0: C = exact fp32 gathers; A = pssm pair, B = W0p pair ----
    f32x4 acc[4];
    #pragma unroll
    for (int t = 0; t < 4; ++t) {
        #pragma unroll
        for (int r = 0; r < 4; ++r) {
            int m = t * 16 + q * 4 + r;          // C/D: row = quad*4+reg
            acc[t][r] = seqT[sidx[m] * 64 + n] + kmerT[kidx[m] * 64 + n];
        }
    }
    #pragma unroll
    for (int t = 0; t < 4; ++t) {
        bf16x8 ah = *(const bf16x8*)&Ph[t * 16 + c16][q * 8];
        bf16x8 al = *(const bf16x8*)&Pl[t * 16 + c16][q * 8];
        acc[t] = __builtin_amdgcn_mfma_f32_16x16x32_bf16(ah, W0H, acc[t], 0, 0, 0);
        acc[t] = __builtin_amdgcn_mfma_f32_16x16x32_bf16(al, W0H, acc[t], 0, 0, 0);
        acc[t] = __builtin_amdgcn_mfma_f32_16x16x32_bf16(ah, W0L, acc[t], 0, 0, 0);
    }
    // split-store h0 -> Ha pair (no relu after layer 0)
    #pragma unroll
    for (int t = 0; t < 4; ++t)
        #pragma unroll
        for (int r = 0; r < 4; ++r) {
            unsigned short h, l; split2t(acc[t][r], h, l);
            Hah[t * 16 + q * 4 + r][n] = h;
            Hal[t * 16 + q * 4 + r][n] = l;
        }
    __syncthreads();   // also fences last pssm reads before Hb overlay writes

    // ---- layer 1: Ha -> Hb (relu) ----
    {
        f32x4 a1[4];
        #pragma unroll
        for (int t = 0; t < 4; ++t) {
            a1[t] = (f32x4){be_n, be_n, be_n, be_n};
            #pragma unroll
            for (int kk = 0; kk < 2; ++kk) {
                bf16x8 ah = *(const bf16x8*)&Hah[t * 16 + c16][kk * 32 + q * 8];
                bf16x8 al = *(const bf16x8*)&Hal[t * 16 + c16][kk * 32 + q * 8];
                a1[t] = __builtin_amdgcn_mfma_f32_16x16x32_bf16(ah, WeH[kk], a1[t], 0, 0, 0);
                a1[t] = __builtin_amdgcn_mfma_f32_16x16x32_bf16(al, WeH[kk], a1[t], 0, 0, 0);
                a1[t] = __builtin_amdgcn_mfma_f32_16x16x32_bf16(ah, WeL[kk], a1[t], 0, 0, 0);
            }
        }
        #pragma unroll
        for (int t = 0; t < 4; ++t)
            #pragma unroll
            for (int r = 0; r < 4; ++r) {
                unsigned short h, l; split2t(fmaxf(a1[t][r], 0.f), h, l);
                Hbh[t * 16 + q * 4 + r][n] = h;
                Hbl[t * 16 + q * 4 + r][n] = l;
            }
        __syncthreads();
    }
    // ---- layer 2: Hb -> Ha (relu) ----
    {
        f32x4 a2[4];
        #pragma unroll
        for (int t = 0; t < 4; ++t) {
            a2[t] = (f32x4){be_n, be_n, be_n, be_n};
            #pragma unroll
            for (int kk = 0; kk < 2; ++kk) {
                bf16x8 ah = *(const bf16x8*)&Hbh[t * 16 + c16][kk * 32 + q * 8];
                bf16x8 al = *(const bf16x8*)&Hbl[t * 16 + c16][kk * 32 + q * 8];
                a2[t] = __builtin_amdgcn_mfma_f32_16x16x32_bf16(ah, WeH[kk], a2[t], 0, 0, 0);
                a2[t] = __builtin_amdgcn_mfma_f32_16x16x32_bf16(al, WeH[kk], a2[t], 0, 0, 0);
                a2[t] = __builtin_amdgcn_mfma_f32_16x16x32_bf16(ah, WeL[kk], a2[t], 0, 0, 0);
            }
        }
        #pragma unroll
        for (int t = 0; t < 4; ++t)
            #pragma unroll
            for (int r = 0; r < 4; ++r) {
                unsigned short h, l; split2t(fmaxf(a2[t][r], 0.f), h, l);
                Hah[t * 16 + q * 4 + r][n] = h;
                Hal[t * 16 + q * 4 + r][n] = l;
            }
        __syncthreads();
    }

    // ---- head: wave wv does M-tile wv; B = W1 pair (cols padded to 16) ----
    {
        f32x4 ah4 = (f32x4){b1h, b1h, b1h, b1h};
        #pragma unroll
        for (int kk = 0; kk < 2; ++kk) {
            bf16x8 ah = *(const bf16x8*)&Hah[wv * 16 + c16][kk * 32 + q * 8];
            bf16x8 al = *(const bf16x8*)&Hal[wv * 16 + c16][kk * 32 + q * 8];
            ah4 = __builtin_amdgcn_mfma_f32_16x16x32_bf16(ah, W1H[kk], ah4, 0, 0, 0);
            ah4 = __builtin_amdgcn_mfma_f32_16x16x32_bf16(al, W1H[kk], ah4, 0, 0, 0);
            ah4 = __builtin_amdgcn_mfma_f32_16x16x32_bf16(ah, W1L[kk], ah4, 0, 0, 0);
        }
        if (c16 < 9) {
            #pragma unroll
            for (int r = 0; r < 4; ++r) {
                int pos = m0 + wv * 16 + q * 4 + r;
                int l = pos >> 8, b = pos & 255;
                srf_t[(l * 9 + c16) * 256 + b] = ah4[r];
            }
        }
    }
}

// ---------- pNeRF phase 1 ----------
__global__ __launch_bounds__(64) void extend_kernel(
    const float* __restrict__ srf_t, float* __restrict__ fragbuf) {
    int frag = blockIdx.x >> 2;
    int bb   = ((blockIdx.x & 3) << 6) + threadIdx.x;

    float3 A  = make_float3(-0.70710678118654752f, 1.22474487139158905f, 0.f);
    float3 Bv = make_float3(-1.41421356237309505f, 0.f, 0.f);
    float3 C  = make_float3(0.f, 0.f, 0.f);

    float ct[9];
    #pragma unroll
    for (int m = 0; m < 9; ++m)
        ct[m] = srf_t[((frag * 32) * 9 + m) * 256 + bb];

    for (int ll = 0; ll < 32; ++ll) {
        float nct[9];
        if (ll < 31) {
            #pragma unroll
            for (int m = 0; m < 9; ++m)
                nct[m] = srf_t[((frag * 32 + ll + 1) * 9 + m) * 256 + bb];
        } else {
            #pragma unroll
            for (int m = 0; m < 9; ++m) nct[m] = 0.f;
        }
        #pragma unroll
        for (int s3 = 0; s3 < 3; ++s3) {
            float3 bc, nn, m3;
            nerf_frame(A, Bv, C, bc, nn, m3);
            float3 d = nerf_place(C, bc, m3, nn,
                                  ct[3 * s3 + 0], ct[3 * s3 + 1], ct[3 * s3 + 2]);
            int row = frag * 96 + ll * 3 + s3;
            fragbuf[(row * 3 + 0) * 256 + bb] = d.x;
            fragbuf[(row * 3 + 1) * 256 + bb] = d.y;
            fragbuf[(row * 3 + 2) * 256 + bb] = d.z;
            A = Bv; Bv = C; C = d;
        }
        #pragma unroll
        for (int m = 0; m < 9; ++m) ct[m] = nct[m];
    }
}

// ---------- pNeRF phase 2a: fragment carry chain ----------
// frames stored as float4 triplets per (frag,bb) for vectorized apply reads:
// [bc.xyz, m3.x] [m3.yz, n.xy] [n.z, C.xyz]
__global__ __launch_bounds__(256) void carry_kernel(
    const float* __restrict__ fragbuf, float4* __restrict__ frames) {
    int bb = threadIdx.x;
    float3 A  = make_float3(-0.70710678118654752f, 1.22474487139158905f, 0.f);
    float3 Bv = make_float3(-1.41421356237309505f, 0.f, 0.f);
    float3 C  = make_float3(0.f, 0.f, 0.f);

    float fr[9];
    #pragma unroll
    for (int t = 0; t < 3; ++t)
        #pragma unroll
        for (int c = 0; c < 3; ++c)
            fr[t * 3 + c] = fragbuf[((93 + t) * 3 + c) * 256 + bb];

    for (int frag = 0; frag < 32; ++frag) {
        float nfr[9];
        if (frag < 31) {
            #pragma unroll
            for (int t = 0; t < 3; ++t)
                #pragma unroll
                for (int c = 0; c < 3; ++c)
                    nfr[t * 3 + c] =
                        fragbuf[(((frag + 1) * 96 + 93 + t) * 3 + c) * 256 + bb];
        } else {
            #pragma unroll
            for (int m = 0; m < 9; ++m) nfr[m] = 0.f;
        }
        float3 bc, nn, m3;
        nerf_frame(A, Bv, C, bc, nn, m3);

        int fb = (frag * 256 + bb) * 3;
        frames[fb + 0] = make_float4(bc.x, bc.y, bc.z, m3.x);
        frames[fb + 1] = make_float4(m3.y, m3.z, nn.x, nn.y);
        frames[fb + 2] = make_float4(nn.z, C.x, C.y, C.z);

        float3 y[3];
        #pragma unroll
        for (int t = 0; t < 3; ++t)
            y[t] = nerf_place(C, bc, m3, nn, fr[t * 3], fr[t * 3 + 1], fr[t * 3 + 2]);
        A = y[0]; Bv = y[1]; C = y[2];
        #pragma unroll
        for (int m = 0; m < 9; ++m) fr[m] = nfr[m];
    }
}

// ---------- pNeRF phase 2b: apply frames; LDS-staged coalesced output ----------
__global__ __launch_bounds__(256) void apply_kernel(
    const float* __restrict__ fragbuf, const float4* __restrict__ frames,
    float* __restrict__ out) {
    __shared__ float sm[768];
    int bb   = threadIdx.x;
    int row  = blockIdx.x;
    int frag = row / 96;

    float fx = fragbuf[(row * 3 + 0) * 256 + bb];
    float fy = fragbuf[(row * 3 + 1) * 256 + bb];
    float fz = fragbuf[(row * 3 + 2) * 256 + bb];

    int fb = (frag * 256 + bb) * 3;
    float4 f0 = frames[fb + 0];
    float4 f1 = frames[fb + 1];
    float4 f2 = frames[fb + 2];

    // f0=[bc.xyz, m3.x] f1=[m3.yz, n.xy] f2=[n.z, C.xyz]
    sm[bb * 3 + 0] = f2.y + f0.x * fx + f0.w * fy + f1.z * fz;
    sm[bb * 3 + 1] = f2.z + f0.y * fx + f1.x * fy + f1.w * fz;
    sm[bb * 3 + 2] = f2.w + f0.z * fx + f1.y * fy + f2.x * fz;
    __syncthreads();

    int base = row * 768;
    out[base + bb]       = sm[bb];
    out[base + 256 + bb] = sm[256 + bb];
    out[base + 512 + bb] = sm[512 + bb];
}

// ---------- host launch ----------
extern "C" void kernel_launch(void* const* d_in, const int* in_sizes, int n_in,
                              void* d_out, int out_size, void* d_ws, size_t ws_size,
                              hipStream_t stream) {
    const int*   seq        = (const int*)d_in[0];
    const int*   kmer       = (const int*)d_in[1];
    const float* pssm       = (const float*)d_in[2];
    const float* seq_embed  = (const float*)d_in[4];
    const float* kmer_embed = (const float*)d_in[5];
    const float* W0         = (const float*)d_in[6];
    const float* b0         = (const float*)d_in[7];
    const float* We         = (const float*)d_in[8];
    const float* be         = (const float*)d_in[9];
    const float* W1         = (const float*)d_in[10];
    const float* b1         = (const float*)d_in[11];

    float* ws      = (float*)d_ws;
    float* kmerT   = ws;                       // 10648*64 = 681472
    float* seqT    = kmerT + 681472;           // 20*64    = 1280
    float* srf_t   = seqT + 1280;              // 1024*9*256 = 2359296
    float* fragbuf = srf_t + 2359296;          // 3072*3*256 = 2359296
    float* frames  = fragbuf + 2359296;        // 32*12*256  = 98304 (float4-accessed)
    float* out     = (float*)d_out;

    // split weight tables alias the fragbuf region: they are consumed by
    // mlp_kernel, which completes before extend_kernel writes fragbuf.
    unsigned short* WeTH  = (unsigned short*)fragbuf;     // 4096 sh
    unsigned short* WeTL  = WeTH + 4096;                  // 4096 sh
    unsigned short* W0pTH = WeTL + 4096;                  // 2048 sh
    unsigned short* W0pTL = W0pTH + 2048;                 // 2048 sh
    unsigned short* W1TH  = W0pTL + 2048;                 // 1024 sh
    unsigned short* W1TL  = W1TH + 1024;                  // 1024 sh

    hipLaunchKernelGGL(prep_kernel, dim3(6), dim3(256), 0, stream,
                       seq_embed, W0, b0, We, W1, seqT,
                       WeTH, WeTL, W0pTH, W0pTL, W1TH, W1TL);
    hipLaunchKernelGGL(kmer_table_kernel, dim3(666), dim3(256), 0, stream,
                       kmer_embed, W0, kmerT);
    hipLaunchKernelGGL(mlp_kernel, dim3(4096), dim3(256), 0, stream,
                       seq, kmer, pssm, seqT, kmerT,
                       WeTH, WeTL, W0pTH, W0pTL, W1TH, W1TL,
                       be, b1, srf_t);
    hipLaunchKernelGGL(extend_kernel, dim3(128), dim3(64), 0, stream,
                       srf_t, fragbuf);
    hipLaunchKernelGGL(carry_kernel, dim3(1), dim3(256), 0, stream,
                       fragbuf, (float4*)frames);
    hipLaunchKernelGGL(apply_kernel, dim3(3072), dim3(256), 0, stream,
                       fragbuf, (float4*)frames, out);
}

// Round 6
// 202.348 us; speedup vs baseline: 1.0975x; 1.0975x over previous
//
#include <hip/hip_runtime.h>
#include <math.h>

#define HPAD 72      // LDS row stride (shorts) for 64-wide rows; 144 B keeps 16B alignment
#define PPAD 40      // LDS row stride for 32-wide pssm rows (80 B, 16B-aligned)

typedef short bf16x8 __attribute__((ext_vector_type(8)));
typedef float f32x4  __attribute__((ext_vector_type(4)));

// round-to-nearest-even float -> bf16 bits
__device__ __forceinline__ unsigned short f2bf(float x) {
    unsigned int u = __float_as_uint(x);
    return (unsigned short)((u + 0x7FFFu + ((u >> 16) & 1u)) >> 16);
}
__device__ __forceinline__ float bf2f(unsigned short h) {
    return __uint_as_float(((unsigned int)h) << 16);
}
// RNE split (precompute path)
__device__ __forceinline__ void split2(float x, unsigned short& h, unsigned short& l) {
    h = f2bf(x);
    l = f2bf(x - bf2f(h));
}
// truncation split (hot path): hi = trunc(x), lo = RNE(x - hi); combined rel err ~2^-17
__device__ __forceinline__ void split2t(float x, unsigned short& h, unsigned short& l) {
    unsigned int u = __float_as_uint(x);
    h = (unsigned short)(u >> 16);
    float r = x - __uint_as_float(u & 0xFFFF0000u);
    l = f2bf(r);
}

__device__ __forceinline__ float inv_norm3(float x, float y, float z) {
    float d = fmaf(x, x, fmaf(y, y, z * z));
    return rsqrtf(fmaxf(d, 1e-24f));
}
__device__ __forceinline__ float3 f3sub(float3 a, float3 b) {
    return make_float3(a.x - b.x, a.y - b.y, a.z - b.z);
}
__device__ __forceinline__ float3 f3cross(float3 a, float3 b) {
    return make_float3(a.y * b.z - a.z * b.y,
                       a.z * b.x - a.x * b.z,
                       a.x * b.y - a.y * b.x);
}
// NeRF frame, parallel normalizations (n from unnormalized w: same direction)
__device__ __forceinline__ void nerf_frame(const float3& A, const float3& Bv,
                                           const float3& C, float3& bc,
                                           float3& n, float3& m3) {
    float3 w  = f3sub(C, Bv);
    float3 v  = f3sub(Bv, A);
    float3 cr = f3cross(v, w);
    float iw = inv_norm3(w.x, w.y, w.z);
    float ic = inv_norm3(cr.x, cr.y, cr.z);
    bc = make_float3(w.x * iw, w.y * iw, w.z * iw);
    n  = make_float3(cr.x * ic, cr.y * ic, cr.z * ic);
    m3 = f3cross(n, bc);
}
__device__ __forceinline__ float3 nerf_place(const float3& C, const float3& bc,
                                             const float3& m3, const float3& n,
                                             float tx, float ty, float tz) {
    return make_float3(
        fmaf(m3.x, ty, fmaf(bc.x, tx, fmaf(n.x, tz, C.x))),
        fmaf(m3.y, ty, fmaf(bc.y, tx, fmaf(n.y, tz, C.y))),
        fmaf(m3.z, ty, fmaf(bc.z, tx, fmaf(n.z, tz, C.z))));
}

// ---------- tables: kmerT (blocks 0..332, LDS-staged W0) + seqT (333..337)
//            + split weight tables (block 338) ----------
__global__ __launch_bounds__(256) void tables_kernel(
    const float* __restrict__ emb, const float* __restrict__ W0,
    const float* __restrict__ se, const float* __restrict__ b0,
    const float* __restrict__ We, const float* __restrict__ W1,
    float* __restrict__ kt, float* __restrict__ seqT,
    unsigned short* __restrict__ WeTH, unsigned short* __restrict__ WeTL,
    unsigned short* __restrict__ W0pTH, unsigned short* __restrict__ W0pTL,
    unsigned short* __restrict__ W1TH, unsigned short* __restrict__ W1TL) {
    __shared__ float W0s[256][64];    // 64 KB: the kmer-slice of W0
    int tid = threadIdx.x;
    if (blockIdx.x < 333) {
        for (int i = tid; i < 16384; i += 256)         // coalesced stage
            W0s[i >> 6][i & 63] = W0[16 * 64 + i];
        __syncthreads();
        int j  = tid & 63;
        int wv = tid >> 6;
        int r0 = blockIdx.x * 32 + wv * 8;             // 333*32 = 10656 >= 10648
        float acc[8] = {0.f,0.f,0.f,0.f,0.f,0.f,0.f,0.f};
        #pragma unroll 8
        for (int k = 0; k < 256; ++k) {
            float w = W0s[k][j];                       // 2-way LDS alias: free
            #pragma unroll
            for (int r = 0; r < 8; ++r) {
                int rr = r0 + r; if (rr > 10647) rr = 10647;   // clamp reads
                acc[r] = fmaf(emb[rr * 256 + k], w, acc[r]);   // uniform -> s_load
            }
        }
        #pragma unroll
        for (int r = 0; r < 8; ++r)
            if (r0 + r < 10648) kt[(r0 + r) * 64 + j] = acc[r];
    } else if (blockIdx.x < 338) {
        // seqT[r][j] = seq_embed[r]@W0[0:16] + b0[j] + 0.5*sum_c W0p[c][j]
        int e = (blockIdx.x - 333) * 256 + tid;        // 0..1279
        int r = e >> 6, j = e & 63;
        float acc = b0[j];
        #pragma unroll
        for (int k = 0; k < 16; ++k)
            acc = fmaf(se[r * 16 + k], W0[k * 64 + j], acc);
        float cs = 0.f;
        #pragma unroll
        for (int c = 0; c < 21; ++c) cs += W0[(272 + c) * 64 + j];
        seqT[r * 64 + j] = acc + 0.5f * cs;
    } else {
        #pragma unroll
        for (int i = 0; i < 16; ++i) {                 // We: 64k x 64n
            int e = i * 256 + tid;
            int k = e >> 6, n = e & 63;
            unsigned short h, l; split2(We[k * 64 + n], h, l);
            WeTH[n * 64 + k] = h; WeTL[n * 64 + k] = l;
        }
        #pragma unroll
        for (int i = 0; i < 8; ++i) {                  // W0p: 32k x 64n (k>=21 zero)
            int e = i * 256 + tid;
            int k = e >> 6, n = e & 63;
            float w = (k < 21) ? W0[(272 + k) * 64 + n] : 0.f;
            unsigned short h, l; split2(w, h, l);
            W0pTH[n * 32 + k] = h; W0pTL[n * 32 + k] = l;
        }
        #pragma unroll
        for (int i = 0; i < 4; ++i) {                  // W1: 64k x 16c (c>=9 zero)
            int e = i * 256 + tid;
            int k = e >> 4, c = e & 15;
            float w = (c < 9) ? W1[k * 9 + c] : 0.f;
            unsigned short h, l; split2(w, h, l);
            W1TH[c * 64 + k] = h; W1TL[c * 64 + k] = l;
        }
    }
}

// ---------- split-bf16 MFMA MLP (unchanged structure; 4 blocks/CU) ----------
__global__ __launch_bounds__(256, 4) void mlp_kernel(
    const int* __restrict__ seq, const int* __restrict__ kmer,
    const float* __restrict__ pssm,
    const float* __restrict__ seqT, const float* __restrict__ kmerT,
    const unsigned short* __restrict__ WeTH, const unsigned short* __restrict__ WeTL,
    const unsigned short* __restrict__ W0pTH, const unsigned short* __restrict__ W0pTL,
    const unsigned short* __restrict__ W1TH, const unsigned short* __restrict__ W1TL,
    const float* __restrict__ be, const float* __restrict__ b1,
    float* __restrict__ srf_t) {

    __shared__ __align__(16) unsigned short Hah[64][HPAD];
    __shared__ __align__(16) unsigned short Hal[64][HPAD];
    __shared__ __align__(16) unsigned short ovl[2][64][HPAD]; // pssm pair, then Hb pair
    __shared__ int sidx[64];
    __shared__ int kidx[64];

    unsigned short (*Ph)[PPAD] = (unsigned short(*)[PPAD])(&ovl[0][0][0]);
    unsigned short (*Pl)[PPAD] = (unsigned short(*)[PPAD])(&ovl[0][0][0] + 2560);
    unsigned short (*Hbh)[HPAD] = ovl[0];
    unsigned short (*Hbl)[HPAD] = ovl[1];

    const int tid  = threadIdx.x;
    const int lane = tid & 63;
    const int wv   = __builtin_amdgcn_readfirstlane(tid >> 6);
    const int q    = lane >> 4;
    const int c16  = lane & 15;
    const int m0   = blockIdx.x * 64;
    const int n    = wv * 16 + c16;

    if (tid < 64) {
        sidx[tid] = seq[m0 + tid];
        kidx[tid] = kmer[m0 + tid];
    }
    for (int i = tid; i < 64 * 21; i += 256) {
        float v = pssm[m0 * 21 + i] - 0.5f;
        unsigned short h, l; split2t(v, h, l);
        Ph[i / 21][i % 21] = h;
        Pl[i / 21][i % 21] = l;
    }
    for (int i = tid; i < 64 * 11; i += 256) {
        Ph[i / 11][21 + (i % 11)] = 0;
        Pl[i / 11][21 + (i % 11)] = 0;
    }

    bf16x8 WeH[2], WeL[2], W1H[2], W1L[2], W0H, W0L;
    #pragma unroll
    for (int kk = 0; kk < 2; ++kk) {
        WeH[kk] = *(const bf16x8*)(WeTH + n * 64 + kk * 32 + q * 8);
        WeL[kk] = *(const bf16x8*)(WeTL + n * 64 + kk * 32 + q * 8);
        W1H[kk] = *(const bf16x8*)(W1TH + c16 * 64 + kk * 32 + q * 8);
        W1L[kk] = *(const bf16x8*)(W1TL + c16 * 64 + kk * 32 + q * 8);
    }
    W0H = *(const bf16x8*)(W0pTH + n * 32 + q * 8);
    W0L = *(const bf16x8*)(W0pTL + n * 32 + q * 8);
    const float be_n = be[n];
    const float b1h  = (c16 < 9) ? b1[c16] : 0.f;
    __syncthreads();

    // layer 0: C = exact fp32 gathers; A = pssm pair, B = W0p pair
    f32x4 acc[4];
    #pragma unroll
    for (int t = 0; t < 4; ++t) {
        #pragma unroll
        for (int r = 0; r < 4; ++r) {
            int m = t * 16 + q * 4 + r;
            acc[t][r] = seqT[sidx[m] * 64 + n] + kmerT[kidx[m] * 64 + n];
        }
    }
    #pragma unroll
    for (int t = 0; t < 4; ++t) {
        bf16x8 ah = *(const bf16x8*)&Ph[t * 16 + c16][q * 8];
        bf16x8 al = *(const bf16x8*)&Pl[t * 16 + c16][q * 8];
        acc[t] = __builtin_amdgcn_mfma_f32_16x16x32_bf16(ah, W0H, acc[t], 0, 0, 0);
        acc[t] = __builtin_amdgcn_mfma_f32_16x16x32_bf16(al, W0H, acc[t], 0, 0, 0);
        acc[t] = __builtin_amdgcn_mfma_f32_16x16x32_bf16(ah, W0L, acc[t], 0, 0, 0);
    }
    #pragma unroll
    for (int t = 0; t < 4; ++t)
        #pragma unroll
        for (int r = 0; r < 4; ++r) {
            unsigned short h, l; split2t(acc[t][r], h, l);
            Hah[t * 16 + q * 4 + r][n] = h;
            Hal[t * 16 + q * 4 + r][n] = l;
        }
    __syncthreads();

    // layer 1: Ha -> Hb (relu)
    {
        f32x4 a1[4];
        #pragma unroll
        for (int t = 0; t < 4; ++t) {
            a1[t] = (f32x4){be_n, be_n, be_n, be_n};
            #pragma unroll
            for (int kk = 0; kk < 2; ++kk) {
                bf16x8 ah = *(const bf16x8*)&Hah[t * 16 + c16][kk * 32 + q * 8];
                bf16x8 al = *(const bf16x8*)&Hal[t * 16 + c16][kk * 32 + q * 8];
                a1[t] = __builtin_amdgcn_mfma_f32_16x16x32_bf16(ah, WeH[kk], a1[t], 0, 0, 0);
                a1[t] = __builtin_amdgcn_mfma_f32_16x16x32_bf16(al, WeH[kk], a1[t], 0, 0, 0);
                a1[t] = __builtin_amdgcn_mfma_f32_16x16x32_bf16(ah, WeL[kk], a1[t], 0, 0, 0);
            }
        }
        #pragma unroll
        for (int t = 0; t < 4; ++t)
            #pragma unroll
            for (int r = 0; r < 4; ++r) {
                unsigned short h, l; split2t(fmaxf(a1[t][r], 0.f), h, l);
                Hbh[t * 16 + q * 4 + r][n] = h;
                Hbl[t * 16 + q * 4 + r][n] = l;
            }
        __syncthreads();
    }
    // layer 2: Hb -> Ha (relu)
    {
        f32x4 a2[4];
        #pragma unroll
        for (int t = 0; t < 4; ++t) {
            a2[t] = (f32x4){be_n, be_n, be_n, be_n};
            #pragma unroll
            for (int kk = 0; kk < 2; ++kk) {
                bf16x8 ah = *(const bf16x8*)&Hbh[t * 16 + c16][kk * 32 + q * 8];
                bf16x8 al = *(const bf16x8*)&Hbl[t * 16 + c16][kk * 32 + q * 8];
                a2[t] = __builtin_amdgcn_mfma_f32_16x16x32_bf16(ah, WeH[kk], a2[t], 0, 0, 0);
                a2[t] = __builtin_amdgcn_mfma_f32_16x16x32_bf16(al, WeH[kk], a2[t], 0, 0, 0);
                a2[t] = __builtin_amdgcn_mfma_f32_16x16x32_bf16(ah, WeL[kk], a2[t], 0, 0, 0);
            }
        }
        #pragma unroll
        for (int t = 0; t < 4; ++t)
            #pragma unroll
            for (int r = 0; r < 4; ++r) {
                unsigned short h, l; split2t(fmaxf(a2[t][r], 0.f), h, l);
                Hah[t * 16 + q * 4 + r][n] = h;
                Hal[t * 16 + q * 4 + r][n] = l;
            }
        __syncthreads();
    }

    // head: wave wv does M-tile wv
    {
        f32x4 ah4 = (f32x4){b1h, b1h, b1h, b1h};
        #pragma unroll
        for (int kk = 0; kk < 2; ++kk) {
            bf16x8 ah = *(const bf16x8*)&Hah[wv * 16 + c16][kk * 32 + q * 8];
            bf16x8 al = *(const bf16x8*)&Hal[wv * 16 + c16][kk * 32 + q * 8];
            ah4 = __builtin_amdgcn_mfma_f32_16x16x32_bf16(ah, W1H[kk], ah4, 0, 0, 0);
            ah4 = __builtin_amdgcn_mfma_f32_16x16x32_bf16(al, W1H[kk], ah4, 0, 0, 0);
            ah4 = __builtin_amdgcn_mfma_f32_16x16x32_bf16(ah, W1L[kk], ah4, 0, 0, 0);
        }
        if (c16 < 9) {
            #pragma unroll
            for (int r = 0; r < 4; ++r) {
                int pos = m0 + wv * 16 + q * 4 + r;
                int l = pos >> 8, b = pos & 255;
                srf_t[(l * 9 + c16) * 256 + b] = ah4[r];
            }
        }
    }
}

// ---------- pNeRF phase 1: extension + per-fragment frame emit ----------
// depth-2 prefetch hides ~600-cycle L3 latency behind ~210 cycles of compute.
// At fragment end, emits local frame F=[bc,m3,n] and endpoint p into FPbuf
// (layout [(frag*12+j)*256+bb]) for the rotation-composition carry.
__global__ __launch_bounds__(64) void extend_kernel(
    const float* __restrict__ srf_t, float* __restrict__ fragbuf,
    float* __restrict__ FPbuf) {
    int frag = blockIdx.x >> 2;
    int bb   = ((blockIdx.x & 3) << 6) + threadIdx.x;

    float3 A  = make_float3(-0.70710678118654752f, 1.22474487139158905f, 0.f);
    float3 Bv = make_float3(-1.41421356237309505f, 0.f, 0.f);
    float3 C  = make_float3(0.f, 0.f, 0.f);

    float ct0[9], ct1[9], ct2[9];
    #pragma unroll
    for (int m = 0; m < 9; ++m) {
        ct0[m] = srf_t[((frag * 32 + 0) * 9 + m) * 256 + bb];
        ct1[m] = srf_t[((frag * 32 + 1) * 9 + m) * 256 + bb];
    }

    for (int ll = 0; ll < 32; ++ll) {
        if (ll < 30) {
            #pragma unroll
            for (int m = 0; m < 9; ++m)
                ct2[m] = srf_t[((frag * 32 + ll + 2) * 9 + m) * 256 + bb];
        } else {
            #pragma unroll
            for (int m = 0; m < 9; ++m) ct2[m] = 0.f;
        }
        #pragma unroll
        for (int s3 = 0; s3 < 3; ++s3) {
            float3 bc, nn, m3;
            nerf_frame(A, Bv, C, bc, nn, m3);
            float3 d = nerf_place(C, bc, m3, nn,
                                  ct0[3 * s3 + 0], ct0[3 * s3 + 1], ct0[3 * s3 + 2]);
            int row = frag * 96 + ll * 3 + s3;
            fragbuf[(row * 3 + 0) * 256 + bb] = d.x;
            fragbuf[(row * 3 + 1) * 256 + bb] = d.y;
            fragbuf[(row * 3 + 2) * 256 + bb] = d.z;
            A = Bv; Bv = C; C = d;
        }
        #pragma unroll
        for (int m = 0; m < 9; ++m) { ct0[m] = ct1[m]; ct1[m] = ct2[m]; }
    }

    // A,Bv,C = local rows 93,94,95: this fragment's local frame + endpoint
    float3 bc, nn, m3;
    nerf_frame(A, Bv, C, bc, nn, m3);
    FPbuf[(frag * 12 + 0)  * 256 + bb] = bc.x;
    FPbuf[(frag * 12 + 1)  * 256 + bb] = bc.y;
    FPbuf[(frag * 12 + 2)  * 256 + bb] = bc.z;
    FPbuf[(frag * 12 + 3)  * 256 + bb] = m3.x;
    FPbuf[(frag * 12 + 4)  * 256 + bb] = m3.y;
    FPbuf[(frag * 12 + 5)  * 256 + bb] = m3.z;
    FPbuf[(frag * 12 + 6)  * 256 + bb] = nn.x;
    FPbuf[(frag * 12 + 7)  * 256 + bb] = nn.y;
    FPbuf[(frag * 12 + 8)  * 256 + bb] = nn.z;
    FPbuf[(frag * 12 + 9)  * 256 + bb] = C.x;
    FPbuf[(frag * 12 + 10) * 256 + bb] = C.y;
    FPbuf[(frag * 12 + 11) * 256 + bb] = C.z;
}

// ---------- pNeRF phase 2a: rotation-composition carry ----------
// Frame construction is rotation-equivariant: Frame(O x + c) = O Frame(x).
// So carry over fragments is (O,c) <- (O*F_f, O*p_f + c) with per-fragment
// constants from extend. All (F,p) staged in LDS -> zero load latency in
// the 32-step serial chain. 4 blocks x 64 batch columns.
__global__ __launch_bounds__(256) void carry_kernel(
    const float* __restrict__ FPbuf, float4* __restrict__ frames) {
    __shared__ float S[384][64];   // 96 KB: [frag*12+j][b-within-block]
    int tid  = threadIdx.x;
    int base = blockIdx.x * 64;
    for (int i = tid; i < 384 * 64; i += 256) {
        int row = i >> 6, col = i & 63;
        S[row][col] = FPbuf[row * 256 + base + col];   // coalesced 256B rows
    }
    __syncthreads();
    if (tid < 64) {
        int bb = base + tid;
        // O = Frame(init) = I (exact to ~1 ulp), c = 0
        float3 ob = make_float3(1.f, 0.f, 0.f);
        float3 om = make_float3(0.f, 1.f, 0.f);
        float3 on = make_float3(0.f, 0.f, 1.f);
        float3 c  = make_float3(0.f, 0.f, 0.f);
        for (int f = 0; f < 32; ++f) {
            int fb = (f * 256 + bb) * 3;
            frames[fb + 0] = make_float4(ob.x, ob.y, ob.z, om.x);
            frames[fb + 1] = make_float4(om.y, om.z, on.x, on.y);
            frames[fb + 2] = make_float4(on.z, c.x, c.y, c.z);

            int r0 = f * 12;
            float3 Fb = make_float3(S[r0+0][tid], S[r0+1][tid], S[r0+2][tid]);
            float3 Fm = make_float3(S[r0+3][tid], S[r0+4][tid], S[r0+5][tid]);
            float3 Fn = make_float3(S[r0+6][tid], S[r0+7][tid], S[r0+8][tid]);
            float3 p  = make_float3(S[r0+9][tid], S[r0+10][tid], S[r0+11][tid]);

            float3 nb = make_float3(
                fmaf(ob.x,Fb.x, fmaf(om.x,Fb.y, on.x*Fb.z)),
                fmaf(ob.y,Fb.x, fmaf(om.y,Fb.y, on.y*Fb.z)),
                fmaf(ob.z,Fb.x, fmaf(om.z,Fb.y, on.z*Fb.z)));
            float3 nm = make_float3(
                fmaf(ob.x,Fm.x, fmaf(om.x,Fm.y, on.x*Fm.z)),
                fmaf(ob.y,Fm.x, fmaf(om.y,Fm.y, on.y*Fm.z)),
                fmaf(ob.z,Fm.x, fmaf(om.z,Fm.y, on.z*Fm.z)));
            float3 nn = make_float3(
                fmaf(ob.x,Fn.x, fmaf(om.x,Fn.y, on.x*Fn.z)),
                fmaf(ob.y,Fn.x, fmaf(om.y,Fn.y, on.y*Fn.z)),
                fmaf(ob.z,Fn.x, fmaf(om.z,Fn.y, on.z*Fn.z)));
            float3 nc = make_float3(
                fmaf(ob.x,p.x, fmaf(om.x,p.y, fmaf(on.x,p.z, c.x))),
                fmaf(ob.y,p.x, fmaf(om.y,p.y, fmaf(on.y,p.z, c.y))),
                fmaf(ob.z,p.x, fmaf(om.z,p.y, fmaf(on.z,p.z, c.z))));
            ob = nb; om = nm; on = nn; c = nc;
        }
    }
}

// ---------- pNeRF phase 2b: apply frames; LDS-staged coalesced output ----------
__global__ __launch_bounds__(256) void apply_kernel(
    const float* __restrict__ fragbuf, const float4* __restrict__ frames,
    float* __restrict__ out) {
    __shared__ float sm[768];
    int bb   = threadIdx.x;
    int row  = blockIdx.x;
    int frag = row / 96;

    float fx = fragbuf[(row * 3 + 0) * 256 + bb];
    float fy = fragbuf[(row * 3 + 1) * 256 + bb];
    float fz = fragbuf[(row * 3 + 2) * 256 + bb];

    int fb = (frag * 256 + bb) * 3;
    float4 f0 = frames[fb + 0];
    float4 f1 = frames[fb + 1];
    float4 f2 = frames[fb + 2];

    sm[bb * 3 + 0] = f2.y + f0.x * fx + f0.w * fy + f1.z * fz;
    sm[bb * 3 + 1] = f2.z + f0.y * fx + f1.x * fy + f1.w * fz;
    sm[bb * 3 + 2] = f2.w + f0.z * fx + f1.y * fy + f2.x * fz;
    __syncthreads();

    int base = row * 768;
    out[base + bb]       = sm[bb];
    out[base + 256 + bb] = sm[256 + bb];
    out[base + 512 + bb] = sm[512 + bb];
}

// ---------- host launch ----------
extern "C" void kernel_launch(void* const* d_in, const int* in_sizes, int n_in,
                              void* d_out, int out_size, void* d_ws, size_t ws_size,
                              hipStream_t stream) {
    const int*   seq        = (const int*)d_in[0];
    const int*   kmer       = (const int*)d_in[1];
    const float* pssm       = (const float*)d_in[2];
    const float* seq_embed  = (const float*)d_in[4];
    const float* kmer_embed = (const float*)d_in[5];
    const float* W0         = (const float*)d_in[6];
    const float* b0         = (const float*)d_in[7];
    const float* We         = (const float*)d_in[8];
    const float* be         = (const float*)d_in[9];
    const float* W1         = (const float*)d_in[10];
    const float* b1         = (const float*)d_in[11];

    float* ws      = (float*)d_ws;
    float* kmerT   = ws;                       // 10648*64 = 681472
    float* seqT    = kmerT + 681472;           // 1280
    float* srf_t   = seqT + 1280;              // 2359296
    float* fragbuf = srf_t + 2359296;          // 2359296
    float* frames  = fragbuf + 2359296;        // 98304 (float4-accessed)
    float* FPbuf   = frames + 98304;           // 98304
    float* out     = (float*)d_out;

    // split weight tables alias fragbuf (consumed by mlp before extend writes it)
    unsigned short* WeTH  = (unsigned short*)fragbuf;
    unsigned short* WeTL  = WeTH + 4096;
    unsigned short* W0pTH = WeTL + 4096;
    unsigned short* W0pTL = W0pTH + 2048;
    unsigned short* W1TH  = W0pTL + 2048;
    unsigned short* W1TL  = W1TH + 1024;

    hipLaunchKernelGGL(tables_kernel, dim3(339), dim3(256), 0, stream,
                       kmer_embed, W0, seq_embed, b0, We, W1,
                       kmerT, seqT, WeTH, WeTL, W0pTH, W0pTL, W1TH, W1TL);
    hipLaunchKernelGGL(mlp_kernel, dim3(4096), dim3(256), 0, stream,
                       seq, kmer, pssm, seqT, kmerT,
                       WeTH, WeTL, W0pTH, W0pTL, W1TH, W1TL,
                       be, b1, srf_t);
    hipLaunchKernelGGL(extend_kernel, dim3(128), dim3(64), 0, stream,
                       srf_t, fragbuf, FPbuf);
    hipLaunchKernelGGL(carry_kernel, dim3(4), dim3(256), 0, stream,
                       FPbuf, (float4*)frames);
    hipLaunchKernelGGL(apply_kernel, dim3(3072), dim3(256), 0, stream,
                       fragbuf, (float4*)frames, out);
}

// Round 7
// 196.872 us; speedup vs baseline: 1.1281x; 1.0278x over previous
//
#include <hip/hip_runtime.h>
#include <math.h>

#define HPAD 72      // LDS row stride (shorts) for 64-wide rows; 144 B, 16B-aligned

typedef short bf16x8 __attribute__((ext_vector_type(8)));
typedef float f32x4  __attribute__((ext_vector_type(4)));

// round-to-nearest-even float -> bf16 bits
__device__ __forceinline__ unsigned short f2bf(float x) {
    unsigned int u = __float_as_uint(x);
    return (unsigned short)((u + 0x7FFFu + ((u >> 16) & 1u)) >> 16);
}
__device__ __forceinline__ float bf2f(unsigned short h) {
    return __uint_as_float(((unsigned int)h) << 16);
}
// RNE split (precompute path)
__device__ __forceinline__ void split2(float x, unsigned short& h, unsigned short& l) {
    h = f2bf(x);
    l = f2bf(x - bf2f(h));
}
// truncation split (hot path): hi = trunc(x), lo = RNE(x - hi); combined rel err ~2^-17
__device__ __forceinline__ void split2t(float x, unsigned short& h, unsigned short& l) {
    unsigned int u = __float_as_uint(x);
    h = (unsigned short)(u >> 16);
    float r = x - __uint_as_float(u & 0xFFFF0000u);
    l = f2bf(r);
}

__device__ __forceinline__ float inv_norm3(float x, float y, float z) {
    float d = fmaf(x, x, fmaf(y, y, z * z));
    return rsqrtf(fmaxf(d, 1e-24f));
}
__device__ __forceinline__ float3 f3sub(float3 a, float3 b) {
    return make_float3(a.x - b.x, a.y - b.y, a.z - b.z);
}
__device__ __forceinline__ float3 f3cross(float3 a, float3 b) {
    return make_float3(a.y * b.z - a.z * b.y,
                       a.z * b.x - a.x * b.z,
                       a.x * b.y - a.y * b.x);
}
// NeRF frame, parallel normalizations (n from unnormalized w: same direction)
__device__ __forceinline__ void nerf_frame(const float3& A, const float3& Bv,
                                           const float3& C, float3& bc,
                                           float3& n, float3& m3) {
    float3 w  = f3sub(C, Bv);
    float3 v  = f3sub(Bv, A);
    float3 cr = f3cross(v, w);
    float iw = inv_norm3(w.x, w.y, w.z);
    float ic = inv_norm3(cr.x, cr.y, cr.z);
    bc = make_float3(w.x * iw, w.y * iw, w.z * iw);
    n  = make_float3(cr.x * ic, cr.y * ic, cr.z * ic);
    m3 = f3cross(n, bc);
}
__device__ __forceinline__ float3 nerf_place(const float3& C, const float3& bc,
                                             const float3& m3, const float3& n,
                                             float tx, float ty, float tz) {
    return make_float3(
        fmaf(m3.x, ty, fmaf(bc.x, tx, fmaf(n.x, tz, C.x))),
        fmaf(m3.y, ty, fmaf(bc.y, tx, fmaf(n.y, tz, C.y))),
        fmaf(m3.z, ty, fmaf(bc.z, tx, fmaf(n.z, tz, C.z))));
}

// ---------- tables ----------
// blocks 0..166 : kmerT = emb @ W0[16:272] via split-bf16 MFMA, all-register,
//                 per-lane VECTOR loads (kills the scalar-path emb streaming
//                 that made every previous kmer-table kernel slow).
// blocks 167..171: seqT. block 172: split weight tables for mlp.
__global__ __launch_bounds__(256) void tables_kernel(
    const float* __restrict__ emb, const float* __restrict__ W0,
    const float* __restrict__ se, const float* __restrict__ b0,
    const float* __restrict__ We, const float* __restrict__ W1,
    float* __restrict__ kt, float* __restrict__ seqT,
    unsigned short* __restrict__ WeTH, unsigned short* __restrict__ WeTL,
    unsigned short* __restrict__ W0pTH, unsigned short* __restrict__ W0pTL,
    unsigned short* __restrict__ W1TH, unsigned short* __restrict__ W1TL) {
    int tid = threadIdx.x;
    if (blockIdx.x < 167) {
        const int lane = tid & 63;
        const int wv   = __builtin_amdgcn_readfirstlane(tid >> 6);
        const int q    = lane >> 4;
        const int c16  = lane & 15;
        const int r0   = blockIdx.x * 64;
        const int n    = wv * 16 + c16;          // this wave's output column

        // B fragments: W0 kmer slice, split, registers (4 x 64B segments/load)
        bf16x8 BH[8], BL[8];
        #pragma unroll
        for (int kt8 = 0; kt8 < 8; ++kt8)
            #pragma unroll
            for (int j = 0; j < 8; ++j) {
                float w = W0[(16 + kt8 * 32 + q * 8 + j) * 64 + n];
                unsigned short h, l; split2t(w, h, l);
                BH[kt8][j] = (short)h; BL[kt8][j] = (short)l;
            }

        f32x4 acc[4];
        #pragma unroll
        for (int t = 0; t < 4; ++t) acc[t] = (f32x4){0.f, 0.f, 0.f, 0.f};

        #pragma unroll
        for (int kt8 = 0; kt8 < 8; ++kt8) {
            #pragma unroll
            for (int t = 0; t < 4; ++t) {
                int rr = r0 + t * 16 + c16;       // A row (clamp OOB reads)
                if (rr > 10647) rr = 10647;
                const float* ap = emb + rr * 256 + kt8 * 32 + q * 8;
                float4 a0 = *(const float4*)ap;       // 32B-aligned
                float4 a1 = *(const float4*)(ap + 4);
                bf16x8 ah, al;
                unsigned short h, l;
                split2t(a0.x, h, l); ah[0] = (short)h; al[0] = (short)l;
                split2t(a0.y, h, l); ah[1] = (short)h; al[1] = (short)l;
                split2t(a0.z, h, l); ah[2] = (short)h; al[2] = (short)l;
                split2t(a0.w, h, l); ah[3] = (short)h; al[3] = (short)l;
                split2t(a1.x, h, l); ah[4] = (short)h; al[4] = (short)l;
                split2t(a1.y, h, l); ah[5] = (short)h; al[5] = (short)l;
                split2t(a1.z, h, l); ah[6] = (short)h; al[6] = (short)l;
                split2t(a1.w, h, l); ah[7] = (short)h; al[7] = (short)l;
                acc[t] = __builtin_amdgcn_mfma_f32_16x16x32_bf16(ah, BH[kt8], acc[t], 0, 0, 0);
                acc[t] = __builtin_amdgcn_mfma_f32_16x16x32_bf16(al, BH[kt8], acc[t], 0, 0, 0);
                acc[t] = __builtin_amdgcn_mfma_f32_16x16x32_bf16(ah, BL[kt8], acc[t], 0, 0, 0);
            }
        }
        #pragma unroll
        for (int t = 0; t < 4; ++t)
            #pragma unroll
            for (int r = 0; r < 4; ++r) {
                int row = r0 + t * 16 + q * 4 + r;    // C/D: row = quad*4+reg
                if (row < 10648) kt[row * 64 + n] = acc[t][r];
            }
    } else if (blockIdx.x < 172) {
        // seqT[r][j] = seq_embed[r]@W0[0:16] + b0[j] + 0.5*sum_c W0p[c][j]
        int e = (blockIdx.x - 167) * 256 + tid;       // 0..1279
        int r = e >> 6, j = e & 63;
        float acc = b0[j];
        #pragma unroll
        for (int k = 0; k < 16; ++k)
            acc = fmaf(se[r * 16 + k], W0[k * 64 + j], acc);
        float cs = 0.f;
        #pragma unroll
        for (int c = 0; c < 21; ++c) cs += W0[(272 + c) * 64 + j];
        seqT[r * 64 + j] = acc + 0.5f * cs;
    } else {
        #pragma unroll
        for (int i = 0; i < 16; ++i) {                // We: 64k x 64n
            int e = i * 256 + tid;
            int k = e >> 6, n = e & 63;
            unsigned short h, l; split2(We[k * 64 + n], h, l);
            WeTH[n * 64 + k] = h; WeTL[n * 64 + k] = l;
        }
        #pragma unroll
        for (int i = 0; i < 8; ++i) {                 // W0p: 32k x 64n (k>=21 zero)
            int e = i * 256 + tid;
            int k = e >> 6, n = e & 63;
            float w = (k < 21) ? W0[(272 + k) * 64 + n] : 0.f;
            unsigned short h, l; split2(w, h, l);
            W0pTH[n * 32 + k] = h; W0pTL[n * 32 + k] = l;
        }
        #pragma unroll
        for (int i = 0; i < 4; ++i) {                 // W1: 64k x 16c (c>=9 zero)
            int e = i * 256 + tid;
            int k = e >> 4, c = e & 15;
            float w = (c < 9) ? W1[k * 9 + c] : 0.f;
            unsigned short h, l; split2(w, h, l);
            W1TH[c * 64 + k] = h; W1TL[c * 64 + k] = l;
        }
    }
}

// ---------- split-bf16 MFMA MLP ----------
// All inputs (pssm A-frags, indices, gathers, weight frags) are DIRECT global
// loads issued from instruction 0 — no staging barrier. 3 barriers total.
__global__ __launch_bounds__(256, 4) void mlp_kernel(
    const int* __restrict__ seq, const int* __restrict__ kmer,
    const float* __restrict__ pssm,
    const float* __restrict__ seqT, const float* __restrict__ kmerT,
    const unsigned short* __restrict__ WeTH, const unsigned short* __restrict__ WeTL,
    const unsigned short* __restrict__ W0pTH, const unsigned short* __restrict__ W0pTL,
    const unsigned short* __restrict__ W1TH, const unsigned short* __restrict__ W1TL,
    const float* __restrict__ be, const float* __restrict__ b1,
    float* __restrict__ srf_t) {

    __shared__ __align__(16) unsigned short Hah[64][HPAD];
    __shared__ __align__(16) unsigned short Hal[64][HPAD];
    __shared__ __align__(16) unsigned short Hbh[64][HPAD];
    __shared__ __align__(16) unsigned short Hbl[64][HPAD];

    const int tid  = threadIdx.x;
    const int lane = tid & 63;
    const int wv   = __builtin_amdgcn_readfirstlane(tid >> 6);
    const int q    = lane >> 4;
    const int c16  = lane & 15;
    const int m0   = blockIdx.x * 64;
    const int n    = wv * 16 + c16;

    // ---- C-init gathers: direct index loads + table gathers (issue early) ----
    f32x4 acc[4];
    #pragma unroll
    for (int t = 0; t < 4; ++t) {
        #pragma unroll
        for (int r = 0; r < 4; ++r) {
            int m  = t * 16 + q * 4 + r;              // C/D row = quad*4+reg
            int s  = seq[m0 + m];
            int km = kmer[m0 + m];
            acc[t][r] = seqT[s * 64 + n] + kmerT[km * 64 + n];
        }
    }

    // ---- pssm A-fragments: direct per-lane loads (L1-resident 5.4 KB region) ----
    bf16x8 PAH[4], PAL[4];
    #pragma unroll
    for (int t = 0; t < 4; ++t) {
        int m = m0 + t * 16 + c16;                    // A row = lane&15
        #pragma unroll
        for (int j = 0; j < 8; ++j) {
            int k = q * 8 + j;
            float v = (k < 21) ? (pssm[m * 21 + k] - 0.5f) : 0.f;
            unsigned short h, l; split2t(v, h, l);
            PAH[t][j] = (short)h; PAL[t][j] = (short)l;
        }
    }

    // ---- weight fragments: 16B loads from pre-split tables ----
    bf16x8 WeH[2], WeL[2], W1H[2], W1L[2], W0H, W0L;
    #pragma unroll
    for (int kk = 0; kk < 2; ++kk) {
        WeH[kk] = *(const bf16x8*)(WeTH + n * 64 + kk * 32 + q * 8);
        WeL[kk] = *(const bf16x8*)(WeTL + n * 64 + kk * 32 + q * 8);
        W1H[kk] = *(const bf16x8*)(W1TH + c16 * 64 + kk * 32 + q * 8);
        W1L[kk] = *(const bf16x8*)(W1TL + c16 * 64 + kk * 32 + q * 8);
    }
    W0H = *(const bf16x8*)(W0pTH + n * 32 + q * 8);
    W0L = *(const bf16x8*)(W0pTL + n * 32 + q * 8);
    const float be_n = be[n];
    const float b1h  = (c16 < 9) ? b1[c16] : 0.f;

    // ---- layer 0 (no barrier needed before: all operands in registers) ----
    #pragma unroll
    for (int t = 0; t < 4; ++t) {
        acc[t] = __builtin_amdgcn_mfma_f32_16x16x32_bf16(PAH[t], W0H, acc[t], 0, 0, 0);
        acc[t] = __builtin_amdgcn_mfma_f32_16x16x32_bf16(PAL[t], W0H, acc[t], 0, 0, 0);
        acc[t] = __builtin_amdgcn_mfma_f32_16x16x32_bf16(PAH[t], W0L, acc[t], 0, 0, 0);
    }
    #pragma unroll
    for (int t = 0; t < 4; ++t)
        #pragma unroll
        for (int r = 0; r < 4; ++r) {
            unsigned short h, l; split2t(acc[t][r], h, l);
            Hah[t * 16 + q * 4 + r][n] = h;
            Hal[t * 16 + q * 4 + r][n] = l;
        }
    __syncthreads();

    // ---- layer 1: Ha -> Hb (relu) ----
    {
        f32x4 a1[4];
        #pragma unroll
        for (int t = 0; t < 4; ++t) {
            a1[t] = (f32x4){be_n, be_n, be_n, be_n};
            #pragma unroll
            for (int kk = 0; kk < 2; ++kk) {
                bf16x8 ah = *(const bf16x8*)&Hah[t * 16 + c16][kk * 32 + q * 8];
                bf16x8 al = *(const bf16x8*)&Hal[t * 16 + c16][kk * 32 + q * 8];
                a1[t] = __builtin_amdgcn_mfma_f32_16x16x32_bf16(ah, WeH[kk], a1[t], 0, 0, 0);
                a1[t] = __builtin_amdgcn_mfma_f32_16x16x32_bf16(al, WeH[kk], a1[t], 0, 0, 0);
                a1[t] = __builtin_amdgcn_mfma_f32_16x16x32_bf16(ah, WeL[kk], a1[t], 0, 0, 0);
            }
        }
        #pragma unroll
        for (int t = 0; t < 4; ++t)
            #pragma unroll
            for (int r = 0; r < 4; ++r) {
                unsigned short h, l; split2t(fmaxf(a1[t][r], 0.f), h, l);
                Hbh[t * 16 + q * 4 + r][n] = h;
                Hbl[t * 16 + q * 4 + r][n] = l;
            }
        __syncthreads();
    }
    // ---- layer 2: Hb -> Ha (relu) ----
    {
        f32x4 a2[4];
        #pragma unroll
        for (int t = 0; t < 4; ++t) {
            a2[t] = (f32x4){be_n, be_n, be_n, be_n};
            #pragma unroll
            for (int kk = 0; kk < 2; ++kk) {
                bf16x8 ah = *(const bf16x8*)&Hbh[t * 16 + c16][kk * 32 + q * 8];
                bf16x8 al = *(const bf16x8*)&Hbl[t * 16 + c16][kk * 32 + q * 8];
                a2[t] = __builtin_amdgcn_mfma_f32_16x16x32_bf16(ah, WeH[kk], a2[t], 0, 0, 0);
                a2[t] = __builtin_amdgcn_mfma_f32_16x16x32_bf16(al, WeH[kk], a2[t], 0, 0, 0);
                a2[t] = __builtin_amdgcn_mfma_f32_16x16x32_bf16(ah, WeL[kk], a2[t], 0, 0, 0);
            }
        }
        #pragma unroll
        for (int t = 0; t < 4; ++t)
            #pragma unroll
            for (int r = 0; r < 4; ++r) {
                unsigned short h, l; split2t(fmaxf(a2[t][r], 0.f), h, l);
                Hah[t * 16 + q * 4 + r][n] = h;
                Hal[t * 16 + q * 4 + r][n] = l;
            }
        __syncthreads();
    }

    // ---- head: wave wv does M-tile wv ----
    {
        f32x4 ah4 = (f32x4){b1h, b1h, b1h, b1h};
        #pragma unroll
        for (int kk = 0; kk < 2; ++kk) {
            bf16x8 ah = *(const bf16x8*)&Hah[wv * 16 + c16][kk * 32 + q * 8];
            bf16x8 al = *(const bf16x8*)&Hal[wv * 16 + c16][kk * 32 + q * 8];
            ah4 = __builtin_amdgcn_mfma_f32_16x16x32_bf16(ah, W1H[kk], ah4, 0, 0, 0);
            ah4 = __builtin_amdgcn_mfma_f32_16x16x32_bf16(al, W1H[kk], ah4, 0, 0, 0);
            ah4 = __builtin_amdgcn_mfma_f32_16x16x32_bf16(ah, W1L[kk], ah4, 0, 0, 0);
        }
        if (c16 < 9) {
            #pragma unroll
            for (int r = 0; r < 4; ++r) {
                int pos = m0 + wv * 16 + q * 4 + r;
                int l = pos >> 8, b = pos & 255;
                srf_t[(l * 9 + c16) * 256 + b] = ah4[r];
            }
        }
    }
}

// ---------- pNeRF phase 1: extension, depth-3 prefetch ----------
__global__ __launch_bounds__(64) void extend_kernel(
    const float* __restrict__ srf_t, float* __restrict__ fragbuf,
    float* __restrict__ FPbuf) {
    int frag = blockIdx.x >> 2;
    int bb   = ((blockIdx.x & 3) << 6) + threadIdx.x;

    float3 A  = make_float3(-0.70710678118654752f, 1.22474487139158905f, 0.f);
    float3 Bv = make_float3(-1.41421356237309505f, 0.f, 0.f);
    float3 C  = make_float3(0.f, 0.f, 0.f);

    float ct0[9], ct1[9], ct2[9], ct3[9];
    #pragma unroll
    for (int m = 0; m < 9; ++m) {
        ct0[m] = srf_t[((frag * 32 + 0) * 9 + m) * 256 + bb];
        ct1[m] = srf_t[((frag * 32 + 1) * 9 + m) * 256 + bb];
        ct2[m] = srf_t[((frag * 32 + 2) * 9 + m) * 256 + bb];
    }

    for (int ll = 0; ll < 32; ++ll) {
        if (ll < 29) {
            #pragma unroll
            for (int m = 0; m < 9; ++m)
                ct3[m] = srf_t[((frag * 32 + ll + 3) * 9 + m) * 256 + bb];
        } else {
            #pragma unroll
            for (int m = 0; m < 9; ++m) ct3[m] = 0.f;
        }
        #pragma unroll
        for (int s3 = 0; s3 < 3; ++s3) {
            float3 bc, nn, m3;
            nerf_frame(A, Bv, C, bc, nn, m3);
            float3 d = nerf_place(C, bc, m3, nn,
                                  ct0[3 * s3 + 0], ct0[3 * s3 + 1], ct0[3 * s3 + 2]);
            int row = frag * 96 + ll * 3 + s3;
            fragbuf[(row * 3 + 0) * 256 + bb] = d.x;
            fragbuf[(row * 3 + 1) * 256 + bb] = d.y;
            fragbuf[(row * 3 + 2) * 256 + bb] = d.z;
            A = Bv; Bv = C; C = d;
        }
        #pragma unroll
        for (int m = 0; m < 9; ++m) { ct0[m] = ct1[m]; ct1[m] = ct2[m]; ct2[m] = ct3[m]; }
    }

    float3 bc, nn, m3;
    nerf_frame(A, Bv, C, bc, nn, m3);
    FPbuf[(frag * 12 + 0)  * 256 + bb] = bc.x;
    FPbuf[(frag * 12 + 1)  * 256 + bb] = bc.y;
    FPbuf[(frag * 12 + 2)  * 256 + bb] = bc.z;
    FPbuf[(frag * 12 + 3)  * 256 + bb] = m3.x;
    FPbuf[(frag * 12 + 4)  * 256 + bb] = m3.y;
    FPbuf[(frag * 12 + 5)  * 256 + bb] = m3.z;
    FPbuf[(frag * 12 + 6)  * 256 + bb] = nn.x;
    FPbuf[(frag * 12 + 7)  * 256 + bb] = nn.y;
    FPbuf[(frag * 12 + 8)  * 256 + bb] = nn.z;
    FPbuf[(frag * 12 + 9)  * 256 + bb] = C.x;
    FPbuf[(frag * 12 + 10) * 256 + bb] = C.y;
    FPbuf[(frag * 12 + 11) * 256 + bb] = C.z;
}

// ---------- pNeRF phase 2a: rotation-composition carry (LDS-staged) ----------
__global__ __launch_bounds__(256) void carry_kernel(
    const float* __restrict__ FPbuf, float4* __restrict__ frames) {
    __shared__ float S[384][64];
    int tid  = threadIdx.x;
    int base = blockIdx.x * 64;
    for (int i = tid; i < 384 * 64; i += 256) {
        int row = i >> 6, col = i & 63;
        S[row][col] = FPbuf[row * 256 + base + col];
    }
    __syncthreads();
    if (tid < 64) {
        int bb = base + tid;
        float3 ob = make_float3(1.f, 0.f, 0.f);
        float3 om = make_float3(0.f, 1.f, 0.f);
        float3 on = make_float3(0.f, 0.f, 1.f);
        float3 c  = make_float3(0.f, 0.f, 0.f);
        for (int f = 0; f < 32; ++f) {
            int fb = (f * 256 + bb) * 3;
            frames[fb + 0] = make_float4(ob.x, ob.y, ob.z, om.x);
            frames[fb + 1] = make_float4(om.y, om.z, on.x, on.y);
            frames[fb + 2] = make_float4(on.z, c.x, c.y, c.z);

            int r0 = f * 12;
            float3 Fb = make_float3(S[r0+0][tid], S[r0+1][tid], S[r0+2][tid]);
            float3 Fm = make_float3(S[r0+3][tid], S[r0+4][tid], S[r0+5][tid]);
            float3 Fn = make_float3(S[r0+6][tid], S[r0+7][tid], S[r0+8][tid]);
            float3 p  = make_float3(S[r0+9][tid], S[r0+10][tid], S[r0+11][tid]);

            float3 nb = make_float3(
                fmaf(ob.x,Fb.x, fmaf(om.x,Fb.y, on.x*Fb.z)),
                fmaf(ob.y,Fb.x, fmaf(om.y,Fb.y, on.y*Fb.z)),
                fmaf(ob.z,Fb.x, fmaf(om.z,Fb.y, on.z*Fb.z)));
            float3 nm = make_float3(
                fmaf(ob.x,Fm.x, fmaf(om.x,Fm.y, on.x*Fm.z)),
                fmaf(ob.y,Fm.x, fmaf(om.y,Fm.y, on.y*Fm.z)),
                fmaf(ob.z,Fm.x, fmaf(om.z,Fm.y, on.z*Fm.z)));
            float3 nn = make_float3(
                fmaf(ob.x,Fn.x, fmaf(om.x,Fn.y, on.x*Fn.z)),
                fmaf(ob.y,Fn.x, fmaf(om.y,Fn.y, on.y*Fn.z)),
                fmaf(ob.z,Fn.x, fmaf(om.z,Fn.y, on.z*Fn.z)));
            float3 nc = make_float3(
                fmaf(ob.x,p.x, fmaf(om.x,p.y, fmaf(on.x,p.z, c.x))),
                fmaf(ob.y,p.x, fmaf(om.y,p.y, fmaf(on.y,p.z, c.y))),
                fmaf(ob.z,p.x, fmaf(om.z,p.y, fmaf(on.z,p.z, c.z))));
            ob = nb; om = nm; on = nn; c = nc;
        }
    }
}

// ---------- pNeRF phase 2b: apply frames; LDS-staged coalesced output ----------
__global__ __launch_bounds__(256) void apply_kernel(
    const float* __restrict__ fragbuf, const float4* __restrict__ frames,
    float* __restrict__ out) {
    __shared__ float sm[768];
    int bb   = threadIdx.x;
    int row  = blockIdx.x;
    int frag = row / 96;

    float fx = fragbuf[(row * 3 + 0) * 256 + bb];
    float fy = fragbuf[(row * 3 + 1) * 256 + bb];
    float fz = fragbuf[(row * 3 + 2) * 256 + bb];

    int fb = (frag * 256 + bb) * 3;
    float4 f0 = frames[fb + 0];
    float4 f1 = frames[fb + 1];
    float4 f2 = frames[fb + 2];

    sm[bb * 3 + 0] = f2.y + f0.x * fx + f0.w * fy + f1.z * fz;
    sm[bb * 3 + 1] = f2.z + f0.y * fx + f1.x * fy + f1.w * fz;
    sm[bb * 3 + 2] = f2.w + f0.z * fx + f1.y * fy + f2.x * fz;
    __syncthreads();

    int base = row * 768;
    out[base + bb]       = sm[bb];
    out[base + 256 + bb] = sm[256 + bb];
    out[base + 512 + bb] = sm[512 + bb];
}

// ---------- host launch ----------
extern "C" void kernel_launch(void* const* d_in, const int* in_sizes, int n_in,
                              void* d_out, int out_size, void* d_ws, size_t ws_size,
                              hipStream_t stream) {
    const int*   seq        = (const int*)d_in[0];
    const int*   kmer       = (const int*)d_in[1];
    const float* pssm       = (const float*)d_in[2];
    const float* seq_embed  = (const float*)d_in[4];
    const float* kmer_embed = (const float*)d_in[5];
    const float* W0         = (const float*)d_in[6];
    const float* b0         = (const float*)d_in[7];
    const float* We         = (const float*)d_in[8];
    const float* be         = (const float*)d_in[9];
    const float* W1         = (const float*)d_in[10];
    const float* b1         = (const float*)d_in[11];

    float* ws      = (float*)d_ws;
    float* kmerT   = ws;                       // 10648*64 = 681472
    float* seqT    = kmerT + 681472;           // 1280
    float* srf_t   = seqT + 1280;              // 2359296
    float* fragbuf = srf_t + 2359296;          // 2359296
    float* frames  = fragbuf + 2359296;        // 98304 (float4-accessed)
    float* FPbuf   = frames + 98304;           // 98304
    float* out     = (float*)d_out;

    // split weight tables alias fragbuf (consumed by mlp before extend writes it)
    unsigned short* WeTH  = (unsigned short*)fragbuf;
    unsigned short* WeTL  = WeTH + 4096;
    unsigned short* W0pTH = WeTL + 4096;
    unsigned short* W0pTL = W0pTH + 2048;
    unsigned short* W1TH  = W0pTL + 2048;
    unsigned short* W1TL  = W1TH + 1024;

    hipLaunchKernelGGL(tables_kernel, dim3(173), dim3(256), 0, stream,
                       kmer_embed, W0, seq_embed, b0, We, W1,
                       kmerT, seqT, WeTH, WeTL, W0pTH, W0pTL, W1TH, W1TL);
    hipLaunchKernelGGL(mlp_kernel, dim3(4096), dim3(256), 0, stream,
                       seq, kmer, pssm, seqT, kmerT,
                       WeTH, WeTL, W0pTH, W0pTL, W1TH, W1TL,
                       be, b1, srf_t);
    hipLaunchKernelGGL(extend_kernel, dim3(128), dim3(64), 0, stream,
                       srf_t, fragbuf, FPbuf);
    hipLaunchKernelGGL(carry_kernel, dim3(4), dim3(256), 0, stream,
                       FPbuf, (float4*)frames);
    hipLaunchKernelGGL(apply_kernel, dim3(3072), dim3(256), 0, stream,
                       fragbuf, (float4*)frames, out);
}